// Round 3
// baseline (387.244 us; speedup 1.0000x reference)
//
#include <hip/hip_runtime.h>
#include <math.h>

#define DM 1024
#define DF 1024
#define NE 8
#define NBIN 16          // (pass, expert) bins: bin = p*8 + e
#define MAXT 136         // max worklist tiles per pass
#define BM 128
#define BN 128
#define BKT 64

typedef __bf16 bf16x8 __attribute__((ext_vector_type(8)));
typedef __bf16 bf16x4 __attribute__((ext_vector_type(4)));
typedef float floatx4 __attribute__((ext_vector_type(4)));

typedef const __attribute__((address_space(1))) unsigned int* gas_t;
typedef __attribute__((address_space(3))) unsigned int* las_t;

__device__ __forceinline__ void ld_lds16(const void* g, void* l) {
    __builtin_amdgcn_global_load_lds((gas_t)g, (las_t)l, 16, 0, 0);
}

// ---------------- ws layout ----------------
// [0, 33.5M)      Xb   bf16[T][1024]
// [33.5M, 50.3M)  WeT  bf16[8][1024][1024]  ([e][n][k])
// [50.3M, ...)    routing: ntiles[2], wl0/wl1 (int4[136] each), blk_cnt, blk_base,
//                 tok_e, tok_w, gath_tok, gath_w

__global__ void convert_weT(const float* __restrict__ We, __bf16* __restrict__ WeT) {
    int n  = blockIdx.x * 256 + threadIdx.x;
    int kc = blockIdx.y * 8;
    int e  = blockIdx.z;
    const float* src = We + ((size_t)e << 20) + (size_t)kc * DF + n;
    bf16x8 v;
#pragma unroll
    for (int j = 0; j < 8; ++j) v[j] = (__bf16)src[(size_t)j * DF];
    *(bf16x8*)&WeT[((size_t)e << 20) + (size_t)n * DM + kc] = v;
}

// fused: gate logits + top-2 + sigmoid + X -> bf16 conversion (X already in regs)
__global__ void gate_kernel(const float4* __restrict__ X4, const float4* __restrict__ Wg4,
                            const float* __restrict__ bg, int* __restrict__ tok_e,
                            float* __restrict__ tok_w, __bf16* __restrict__ Xb, int T) {
    int wid  = threadIdx.x >> 6;
    int lane = threadIdx.x & 63;
    int t = blockIdx.x * 4 + wid;
    if (t >= T) return;
    float acc[NE] = {};
    float4 xs[4];
#pragma unroll
    for (int c = 0; c < 4; ++c) {
        float4 xv = X4[(size_t)t * 256 + c * 64 + lane];
        xs[c] = xv;
#pragma unroll
        for (int e = 0; e < NE; ++e) {
            float4 wv = Wg4[e * 256 + c * 64 + lane];
            acc[e] += xv.x * wv.x + xv.y * wv.y + xv.z * wv.z + xv.w * wv.w;
        }
    }
    // convert this token's X row to bf16 (coalesced 8B stores)
#pragma unroll
    for (int c = 0; c < 4; ++c) {
        bf16x4 v;
        v[0] = (__bf16)xs[c].x; v[1] = (__bf16)xs[c].y;
        v[2] = (__bf16)xs[c].z; v[3] = (__bf16)xs[c].w;
        *(bf16x4*)&Xb[(size_t)t * DM + c * 256 + lane * 4] = v;
    }
#pragma unroll
    for (int e = 0; e < NE; ++e) {
#pragma unroll
        for (int off = 32; off > 0; off >>= 1)
            acc[e] += __shfl_down(acc[e], off, 64);
    }
    if (lane == 0) {
        float l[NE];
#pragma unroll
        for (int e = 0; e < NE; ++e) l[e] = acc[e] + bg[e];
        int b0 = 0; float v0 = l[0];
        for (int e = 1; e < NE; ++e) if (l[e] > v0) { v0 = l[e]; b0 = e; }
        int b1 = -1; float v1 = -3.4e38f;
        for (int e = 0; e < NE; ++e) if (e != b0 && l[e] > v1) { v1 = l[e]; b1 = e; }
        tok_e[2 * t]     = b0;  tok_e[2 * t + 1] = b1;
        tok_w[2 * t]     = 1.f / (1.f + expf(-v0));
        tok_w[2 * t + 1] = 1.f / (1.f + expf(-v1));
    }
}

// per-block 16-bin histogram via ballots (no global atomics)
__global__ void hist_kernel(const int* __restrict__ tok_e, int* __restrict__ blk_cnt, int n) {
    int b = blockIdx.x, tid = threadIdx.x;
    int idx  = b * 256 + tid;
    int lane = tid & 63, w = tid >> 6;
    int bin = (idx < n) ? ((idx & 1) * NE + tok_e[idx]) : -1;
    __shared__ int wc[4][NBIN];
#pragma unroll
    for (int bx = 0; bx < NBIN; ++bx) {
        unsigned long long m = __ballot(bin == bx);
        if (lane == 0) wc[w][bx] = (int)__popcll(m);
    }
    __syncthreads();
    if (tid < NBIN) blk_cnt[b * NBIN + tid] = wc[0][tid] + wc[1][tid] + wc[2][tid] + wc[3][tid];
}

// scan over blocks + bins, and build the two GEMM worklists
__global__ void scan_kernel(const int* __restrict__ blk_cnt, int* __restrict__ blk_base,
                            int4* __restrict__ wl, int* __restrict__ ntiles, int NB) {
    __shared__ int c[2048];
    __shared__ int tot[NBIN], base[NBIN];
    int tid = threadIdx.x;
    for (int i = tid; i < NB * NBIN; i += 256) c[i] = blk_cnt[i];
    __syncthreads();
    if (tid < NBIN) {
        int s = 0;
        for (int b = 0; b < NB; ++b) s += c[b * NBIN + tid];
        tot[tid] = s;
    }
    __syncthreads();
    if (tid == 0) {
        int s = 0;
        for (int b = 0; b < NBIN; ++b) { base[b] = s; s += tot[b]; }
    }
    __syncthreads();
    if (tid < NBIN) {
        int run = base[tid];
        for (int b = 0; b < NB; ++b) { int v = c[b * NBIN + tid]; c[b * NBIN + tid] = run; run += v; }
    }
    __syncthreads();
    for (int i = tid; i < NB * NBIN; i += 256) blk_base[i] = c[i];
    if (tid == 0) {
        for (int p = 0; p < 2; ++p) {
            int nt = 0;
            for (int e = 0; e < NE; ++e) {
                int bin = p * NE + e;
                int cnt = tot[bin], sg = base[bin];
                for (int r0 = 0; r0 < cnt; r0 += BM)
                    wl[p * MAXT + nt++] = make_int4(e, r0, sg, cnt);
            }
            ntiles[p] = nt;
        }
    }
}

// deterministic rank-based scatter into 16 bins (no global atomics)
__global__ void scatter_kernel(const int* __restrict__ tok_e, const float* __restrict__ tok_w,
                               const int* __restrict__ blk_base, int* __restrict__ gath_tok,
                               float* __restrict__ gath_w, int n) {
    int b = blockIdx.x, tid = threadIdx.x;
    int idx  = b * 256 + tid;
    int lane = tid & 63, w = tid >> 6;
    bool act = idx < n;
    int bin = act ? ((idx & 1) * NE + tok_e[idx]) : -1;
    __shared__ int wc[4][NBIN], wb[4][NBIN];
    int myrank = 0;
#pragma unroll
    for (int bx = 0; bx < NBIN; ++bx) {
        unsigned long long m = __ballot(bin == bx);
        if (lane == 0) wc[w][bx] = (int)__popcll(m);
        if (bin == bx) myrank = (int)__popcll(m & ((1ull << lane) - 1ull));
    }
    __syncthreads();
    if (tid < NBIN) {
        int run = blk_base[b * NBIN + tid];
#pragma unroll
        for (int wv = 0; wv < 4; ++wv) { wb[wv][tid] = run; run += wc[wv][tid]; }
    }
    __syncthreads();
    if (act) {
        int pos = wb[w][bin] + myrank;
        gath_tok[pos] = idx >> 1;
        gath_w[pos]   = tok_w[idx];
    }
}

template <bool ACC>
__global__ __launch_bounds__(256) void expert_gemm_mfma(
        const __bf16* __restrict__ Xb, const __bf16* __restrict__ WeT,
        const float* __restrict__ be, const int4* __restrict__ wl,
        const int* __restrict__ ntiles, const int* __restrict__ gtok,
        const float* __restrict__ gw, float* __restrict__ out) {
    if ((int)blockIdx.x >= ntiles[0]) return;
    int4 ent = wl[blockIdx.x];
    int e = ent.x, row0 = ent.y, seg = ent.z, n_e = ent.w;
    int col0 = blockIdx.y * BN;

    // swizzled lane-linear layout: elem(r,k) at r*64 + ((k>>3)^(r&7))*8 + (k&7)
    // double-buffered: statically addressed (no runtime buffer index)
    __shared__ __align__(16) __bf16 As0[BM * BKT];
    __shared__ __align__(16) __bf16 As1[BM * BKT];
    __shared__ __align__(16) __bf16 Bs0[BM * BKT];
    __shared__ __align__(16) __bf16 Bs1[BM * BKT];
    __shared__ int   s_tok[BM];
    __shared__ float s_w[BM];

    int tid = threadIdx.x;
    if (tid < BM) {
        int gr = row0 + tid;
        s_tok[tid] = (gr < n_e) ? gtok[seg + gr] : gtok[seg];
        s_w[tid]   = (gr < n_e) ? gw[seg + gr]   : 0.f;
    }
    __syncthreads();

    int lane = tid & 63, w = tid >> 6;
    int lr = lane >> 3;              // row-within-8
    int kc = (lane & 7) ^ lr;        // XOR-swizzled k-chunk

    const __bf16* aptr[4];
    const __bf16* bptr[4];
#pragma unroll
    for (int p = 0; p < 4; ++p) {
        int r = p * 32 + w * 8 + lr;
        aptr[p] = Xb + (size_t)s_tok[r] * DM + kc * 8;
        bptr[p] = WeT + ((size_t)e << 20) + (size_t)(col0 + r) * DM + kc * 8;
    }

    int wr = (w >> 1) * 64, wcc = (w & 1) * 64;
    int m16 = lane & 15, q = lane >> 4;
    int rsw = m16 & 7;

    floatx4 acc[4][4] = {};

    auto stage = [&](int koff, __bf16* AD, __bf16* BD) {
#pragma unroll
        for (int p = 0; p < 4; ++p) ld_lds16(aptr[p] + koff, &AD[(p * 4 + w) * 512]);
#pragma unroll
        for (int p = 0; p < 4; ++p) ld_lds16(bptr[p] + koff, &BD[(p * 4 + w) * 512]);
    };
    auto compute = [&](const __bf16* AS, const __bf16* BS) {
#pragma unroll
        for (int kt = 0; kt < 2; ++kt) {
            bf16x8 af[4], bfr[4];
#pragma unroll
            for (int i = 0; i < 4; ++i)
                af[i] = *(const bf16x8*)&AS[(wr + i * 16 + m16) * 64 + ((kt * 4 + q) ^ rsw) * 8];
#pragma unroll
            for (int i = 0; i < 4; ++i)
                bfr[i] = *(const bf16x8*)&BS[(wcc + i * 16 + m16) * 64 + ((kt * 4 + q) ^ rsw) * 8];
#pragma unroll
            for (int i = 0; i < 4; ++i)
#pragma unroll
                for (int j = 0; j < 4; ++j)
                    acc[i][j] = __builtin_amdgcn_mfma_f32_16x16x32_bf16(af[i], bfr[j], acc[i][j], 0, 0, 0);
        }
    };

    // prologue: stage K-tile 0 into buffer 0
    stage(0, As0, Bs0);
    __syncthreads();   // drains vmcnt(0): buf0 ready

    // 2-phase pipeline, unrolled x2 over static buffers; one barrier per K-step
    for (int k0 = 0; k0 < DM; k0 += 2 * BKT) {
        // phase A: prefetch tile k0+BKT into buf1 (flies under MFMAs), compute buf0
        stage(k0 + BKT, As1, Bs1);
        compute(As0, Bs0);
        __syncthreads();           // drains prefetch: buf1 ready; buf0 reads done
        // phase B: prefetch tile k0+2*BKT into buf0 (if any), compute buf1
        if (k0 + 2 * BKT < DM) stage(k0 + 2 * BKT, As0, Bs0);
        compute(As1, Bs1);
        __syncthreads();           // buf0 ready for next iter; buf1 reads done
    }

    // epilogue: plain stores (pass 0) or unique-writer read-add-store (pass 1)
    // C/D layout: col=lane&15, row=q*4+reg
#pragma unroll
    for (int j = 0; j < 4; ++j) {
        int c = col0 + wcc + j * 16 + m16;
        float bias = be[e * DF + c];
#pragma unroll
        for (int i = 0; i < 4; ++i) {
#pragma unroll
            for (int rg = 0; rg < 4; ++rg) {
                int rl = wr + i * 16 + q * 4 + rg;
                int gr = row0 + rl;
                if (gr < n_e) {
                    size_t o = (size_t)s_tok[rl] * DF + c;
                    float v = s_w[rl] * (acc[i][j][rg] + bias);
                    if (ACC) out[o] += v;
                    else     out[o] = v;
                }
            }
        }
    }
}

extern "C" void kernel_launch(void* const* d_in, const int* in_sizes, int n_in,
                              void* d_out, int out_size, void* d_ws, size_t ws_size,
                              hipStream_t stream) {
    const float* x  = (const float*)d_in[0];
    const float* Wg = (const float*)d_in[1];
    const float* bg = (const float*)d_in[2];
    const float* We = (const float*)d_in[3];
    const float* be = (const float*)d_in[4];
    float* out = (float*)d_out;

    int T = in_sizes[0] / DM;
    int n_slots = 2 * T;
    int NB = (n_slots + 255) / 256;

    char* ws = (char*)d_ws;
    size_t xb_bytes  = (size_t)T * DM * 2;
    size_t weT_bytes = (size_t)NE * DM * DF * 2;
    __bf16* Xb  = (__bf16*)ws;
    __bf16* WeT = (__bf16*)(ws + xb_bytes);
    char* rt = ws + xb_bytes + weT_bytes;
    int*   ntiles    = (int*)(rt + 0);
    int4*  wl        = (int4*)(rt + 64);                     // 2 * 136 int4
    int*   blk_cnt   = (int*)(rt + 64 + 2 * MAXT * 16);
    int*   blk_base  = (int*)((char*)blk_cnt + (size_t)NB * NBIN * 4);
    int*   tok_e     = (int*)((char*)blk_base + (size_t)NB * NBIN * 4);
    float* tok_w     = (float*)((char*)tok_e + (size_t)n_slots * 4);
    int*   gath_tok  = (int*)((char*)tok_w + (size_t)n_slots * 4);
    float* gath_w    = (float*)((char*)gath_tok + (size_t)n_slots * 4);

    convert_weT<<<dim3(DF / 256, DM / 8, NE), 256, 0, stream>>>(We, WeT);
    gate_kernel<<<(T + 3) / 4, 256, 0, stream>>>((const float4*)x, (const float4*)Wg,
                                                 bg, tok_e, tok_w, Xb, T);
    hist_kernel<<<NB, 256, 0, stream>>>(tok_e, blk_cnt, n_slots);
    scan_kernel<<<1, 256, 0, stream>>>(blk_cnt, blk_base, wl, ntiles, NB);
    scatter_kernel<<<NB, 256, 0, stream>>>(tok_e, tok_w, blk_base, gath_tok, gath_w, n_slots);

    dim3 grid(MAXT, DF / BN);
    expert_gemm_mfma<false><<<grid, 256, 0, stream>>>(Xb, WeT, be, wl, ntiles,
                                                      gath_tok, gath_w, out);
    expert_gemm_mfma<true><<<grid, 256, 0, stream>>>(Xb, WeT, be, wl + MAXT, ntiles + 1,
                                                     gath_tok, gath_w, out);
}

// Round 5
// 315.697 us; speedup vs baseline: 1.2266x; 1.2266x over previous
//
#include <hip/hip_runtime.h>
#include <math.h>

#define DM 1024
#define DF 1024
#define NE 8
#define NBIN 16          // (pass, expert) bins: bin = p*8 + e
#define MAXT 136         // max worklist tiles per pass
#define BM 128
#define BN 128
#define BKT 64

typedef __bf16 bf16x8 __attribute__((ext_vector_type(8)));
typedef __bf16 bf16x4 __attribute__((ext_vector_type(4)));
typedef float floatx4 __attribute__((ext_vector_type(4)));

typedef const __attribute__((address_space(1))) unsigned int* gas_t;
typedef __attribute__((address_space(3))) unsigned int* las_t;

__device__ __forceinline__ void ld_lds16(const void* g, void* l) {
    __builtin_amdgcn_global_load_lds((gas_t)g, (las_t)l, 16, 0, 0);
}

// ---------------- ws layout ----------------
// [0, 33.5M)      Xb   bf16[T][1024]
// [33.5M, 50.3M)  WeT  bf16[8][1024][1024]  ([e][n][k])
// [50.3M, ...)    routing: ntiles[2], wl0/wl1 (int4[136] each), blk_cnt, blk_base,
//                 tok_e, tok_w, gath_tok, gath_w

__global__ void convert_weT(const float* __restrict__ We, __bf16* __restrict__ WeT) {
    int n  = blockIdx.x * 256 + threadIdx.x;
    int kc = blockIdx.y * 8;
    int e  = blockIdx.z;
    const float* src = We + ((size_t)e << 20) + (size_t)kc * DF + n;
    bf16x8 v;
#pragma unroll
    for (int j = 0; j < 8; ++j) v[j] = (__bf16)src[(size_t)j * DF];
    *(bf16x8*)&WeT[((size_t)e << 20) + (size_t)n * DM + kc] = v;
}

// fused: gate logits + top-2 + sigmoid + X -> bf16 conversion (X already in regs)
__global__ void gate_kernel(const float4* __restrict__ X4, const float4* __restrict__ Wg4,
                            const float* __restrict__ bg, int* __restrict__ tok_e,
                            float* __restrict__ tok_w, __bf16* __restrict__ Xb, int T) {
    int wid  = threadIdx.x >> 6;
    int lane = threadIdx.x & 63;
    int t = blockIdx.x * 4 + wid;
    if (t >= T) return;
    float acc[NE] = {};
    float4 xs[4];
#pragma unroll
    for (int c = 0; c < 4; ++c) {
        float4 xv = X4[(size_t)t * 256 + c * 64 + lane];
        xs[c] = xv;
#pragma unroll
        for (int e = 0; e < NE; ++e) {
            float4 wv = Wg4[e * 256 + c * 64 + lane];
            acc[e] += xv.x * wv.x + xv.y * wv.y + xv.z * wv.z + xv.w * wv.w;
        }
    }
    // convert this token's X row to bf16 (coalesced 8B stores)
#pragma unroll
    for (int c = 0; c < 4; ++c) {
        bf16x4 v;
        v[0] = (__bf16)xs[c].x; v[1] = (__bf16)xs[c].y;
        v[2] = (__bf16)xs[c].z; v[3] = (__bf16)xs[c].w;
        *(bf16x4*)&Xb[(size_t)t * DM + c * 256 + lane * 4] = v;
    }
#pragma unroll
    for (int e = 0; e < NE; ++e) {
#pragma unroll
        for (int off = 32; off > 0; off >>= 1)
            acc[e] += __shfl_down(acc[e], off, 64);
    }
    if (lane == 0) {
        float l[NE];
#pragma unroll
        for (int e = 0; e < NE; ++e) l[e] = acc[e] + bg[e];
        int b0 = 0; float v0 = l[0];
        for (int e = 1; e < NE; ++e) if (l[e] > v0) { v0 = l[e]; b0 = e; }
        int b1 = -1; float v1 = -3.4e38f;
        for (int e = 0; e < NE; ++e) if (e != b0 && l[e] > v1) { v1 = l[e]; b1 = e; }
        tok_e[2 * t]     = b0;  tok_e[2 * t + 1] = b1;
        tok_w[2 * t]     = 1.f / (1.f + expf(-v0));
        tok_w[2 * t + 1] = 1.f / (1.f + expf(-v1));
    }
}

// per-block 16-bin histogram via ballots (no global atomics)
__global__ void hist_kernel(const int* __restrict__ tok_e, int* __restrict__ blk_cnt, int n) {
    int b = blockIdx.x, tid = threadIdx.x;
    int idx  = b * 256 + tid;
    int lane = tid & 63, w = tid >> 6;
    int bin = (idx < n) ? ((idx & 1) * NE + tok_e[idx]) : -1;
    __shared__ int wc[4][NBIN];
#pragma unroll
    for (int bx = 0; bx < NBIN; ++bx) {
        unsigned long long m = __ballot(bin == bx);
        if (lane == 0) wc[w][bx] = (int)__popcll(m);
    }
    __syncthreads();
    if (tid < NBIN) blk_cnt[b * NBIN + tid] = wc[0][tid] + wc[1][tid] + wc[2][tid] + wc[3][tid];
}

// scan over blocks + bins, and build the two GEMM worklists
__global__ void scan_kernel(const int* __restrict__ blk_cnt, int* __restrict__ blk_base,
                            int4* __restrict__ wl, int* __restrict__ ntiles, int NB) {
    __shared__ int c[2048];
    __shared__ int tot[NBIN], base[NBIN];
    int tid = threadIdx.x;
    for (int i = tid; i < NB * NBIN; i += 256) c[i] = blk_cnt[i];
    __syncthreads();
    if (tid < NBIN) {
        int s = 0;
        for (int b = 0; b < NB; ++b) s += c[b * NBIN + tid];
        tot[tid] = s;
    }
    __syncthreads();
    if (tid == 0) {
        int s = 0;
        for (int b = 0; b < NBIN; ++b) { base[b] = s; s += tot[b]; }
    }
    __syncthreads();
    if (tid < NBIN) {
        int run = base[tid];
        for (int b = 0; b < NB; ++b) { int v = c[b * NBIN + tid]; c[b * NBIN + tid] = run; run += v; }
    }
    __syncthreads();
    for (int i = tid; i < NB * NBIN; i += 256) blk_base[i] = c[i];
    if (tid == 0) {
        for (int p = 0; p < 2; ++p) {
            int nt = 0;
            for (int e = 0; e < NE; ++e) {
                int bin = p * NE + e;
                int cnt = tot[bin], sg = base[bin];
                for (int r0 = 0; r0 < cnt; r0 += BM)
                    wl[p * MAXT + nt++] = make_int4(e, r0, sg, cnt);
            }
            ntiles[p] = nt;
        }
    }
}

// deterministic rank-based scatter into 16 bins (no global atomics)
__global__ void scatter_kernel(const int* __restrict__ tok_e, const float* __restrict__ tok_w,
                               const int* __restrict__ blk_base, int* __restrict__ gath_tok,
                               float* __restrict__ gath_w, int n) {
    int b = blockIdx.x, tid = threadIdx.x;
    int idx  = b * 256 + tid;
    int lane = tid & 63, w = tid >> 6;
    bool act = idx < n;
    int bin = act ? ((idx & 1) * NE + tok_e[idx]) : -1;
    __shared__ int wc[4][NBIN], wb[4][NBIN];
    int myrank = 0;
#pragma unroll
    for (int bx = 0; bx < NBIN; ++bx) {
        unsigned long long m = __ballot(bin == bx);
        if (lane == 0) wc[w][bx] = (int)__popcll(m);
        if (bin == bx) myrank = (int)__popcll(m & ((1ull << lane) - 1ull));
    }
    __syncthreads();
    if (tid < NBIN) {
        int run = blk_base[b * NBIN + tid];
#pragma unroll
        for (int wv = 0; wv < 4; ++wv) { wb[wv][tid] = run; run += wc[wv][tid]; }
    }
    __syncthreads();
    if (act) {
        int pos = wb[w][bin] + myrank;
        gath_tok[pos] = idx >> 1;
        gath_w[pos]   = tok_w[idx];
    }
}

template <bool ACC>
__global__ __launch_bounds__(256) void expert_gemm_mfma(
        const __bf16* __restrict__ Xb, const __bf16* __restrict__ WeT,
        const float* __restrict__ be, const int4* __restrict__ wl,
        const int* __restrict__ ntiles, const int* __restrict__ gtok,
        const float* __restrict__ gw, float* __restrict__ out) {
    // chunked XCD swizzle (bijective: 1088 = 8 * 136): XCD k gets 17 consecutive
    // worklist tiles x all 8 col-blocks -> A-rows and B-panels L2-resident per XCD
    int sw = (blockIdx.x & 7) * MAXT + (blockIdx.x >> 3);
    int tix  = sw >> 3;
    int col0 = (sw & 7) * BN;
    if (tix >= ntiles[0]) return;
    int4 ent = wl[tix];
    int e = ent.x, row0 = ent.y, seg = ent.z, n_e = ent.w;

    // staging LDS (64 KB), reused as the f32 C-transpose buffer in the epilogue
    __shared__ __align__(16) char smem_raw[64 * 1024];
    __bf16* As0 = (__bf16*)(smem_raw);
    __bf16* As1 = (__bf16*)(smem_raw + 16384);
    __bf16* Bs0 = (__bf16*)(smem_raw + 32768);
    __bf16* Bs1 = (__bf16*)(smem_raw + 49152);
    __shared__ int   s_tok[BM];
    __shared__ float s_w[BM];

    int tid = threadIdx.x;
    if (tid < BM) {
        int gr = row0 + tid;
        s_tok[tid] = (gr < n_e) ? gtok[seg + gr] : gtok[seg];
        s_w[tid]   = (gr < n_e) ? gw[seg + gr]   : 0.f;
    }
    __syncthreads();

    int lane = tid & 63, w = tid >> 6;
    int lr = lane >> 3;              // row-within-8
    int kc = (lane & 7) ^ lr;        // XOR-swizzled k-chunk

    const __bf16* aptr[4];
    const __bf16* bptr[4];
#pragma unroll
    for (int p = 0; p < 4; ++p) {
        int r = p * 32 + w * 8 + lr;
        aptr[p] = Xb + (size_t)s_tok[r] * DM + kc * 8;
        bptr[p] = WeT + ((size_t)e << 20) + (size_t)(col0 + r) * DM + kc * 8;
    }

    int wr = (w >> 1) * 64, wcc = (w & 1) * 64;
    int m16 = lane & 15, q = lane >> 4;
    int rsw = m16 & 7;

    floatx4 acc[4][4] = {};

    auto stage = [&](int koff, __bf16* AD, __bf16* BD) {
#pragma unroll
        for (int p = 0; p < 4; ++p) ld_lds16(aptr[p] + koff, &AD[(p * 4 + w) * 512]);
#pragma unroll
        for (int p = 0; p < 4; ++p) ld_lds16(bptr[p] + koff, &BD[(p * 4 + w) * 512]);
    };
    auto compute = [&](const __bf16* AS, const __bf16* BS) {
#pragma unroll
        for (int kt = 0; kt < 2; ++kt) {
            bf16x8 af[4], bfr[4];
#pragma unroll
            for (int i = 0; i < 4; ++i)
                af[i] = *(const bf16x8*)&AS[(wr + i * 16 + m16) * 64 + ((kt * 4 + q) ^ rsw) * 8];
#pragma unroll
            for (int i = 0; i < 4; ++i)
                bfr[i] = *(const bf16x8*)&BS[(wcc + i * 16 + m16) * 64 + ((kt * 4 + q) ^ rsw) * 8];
#pragma unroll
            for (int i = 0; i < 4; ++i)
#pragma unroll
                for (int j = 0; j < 4; ++j)
                    acc[i][j] = __builtin_amdgcn_mfma_f32_16x16x32_bf16(af[i], bfr[j], acc[i][j], 0, 0, 0);
        }
    };

    // prologue: stage K-tile 0 into buffer 0
    stage(0, As0, Bs0);
    __syncthreads();   // drains vmcnt(0): buf0 ready

    // 2-phase pipeline, unrolled x2 over static buffers; one barrier per K-step
    for (int k0 = 0; k0 < DM; k0 += 2 * BKT) {
        stage(k0 + BKT, As1, Bs1);
        compute(As0, Bs0);
        __syncthreads();
        if (k0 + 2 * BKT < DM) stage(k0 + 2 * BKT, As0, Bs0);
        compute(As1, Bs1);
        __syncthreads();           // after final iter: all LDS reads done
    }

    // ---- epilogue: transpose acc through LDS (XOR-swizzled quads), then
    // full-line float4 writes / RMW: 4-lane groups cover 64-B contiguous runs ----
    float* Cs = (float*)smem_raw;   // 128 x 128 f32 = 64 KB, exactly the staging LDS
    // C/D fragment layout: row = wr + i*16 + q*4 + rg, col = wcc + j*16 + m16
#pragma unroll
    for (int j = 0; j < 4; ++j) {
#pragma unroll
        for (int i = 0; i < 4; ++i) {
#pragma unroll
            for (int rg = 0; rg < 4; ++rg) {
                int rl = wr + i * 16 + q * 4 + rg;
                int cl = wcc + j * 16 + m16;
                int quad = (cl >> 2) ^ (rl & 31);       // swizzle: spread quads across banks
                Cs[rl * 128 + quad * 4 + (cl & 3)] = acc[i][j][rg];
            }
        }
    }
    __syncthreads();

    // reader: 4 lanes/row, each thread covers TWO row-halves (rh) -> all 128 rows
#pragma unroll
    for (int rh = 0; rh < 2; ++rh) {
        int rr = w * 32 + rh * 16 + (lane >> 2);
        int gr2 = row0 + rr;
        if (gr2 < n_e) {
            int tok = s_tok[rr];
            float wgt = s_w[rr];
            float* orow = out + (size_t)tok * DF + col0;
            const float* brow = be + e * DF + col0;
#pragma unroll
            for (int k = 0; k < 8; ++k) {
                int cq = k * 4 + (lane & 3);            // logical quad 0..31
                int c4 = cq * 4;
                floatx4 v  = *(const floatx4*)&Cs[rr * 128 + ((cq ^ (rr & 31)) * 4)];
                floatx4 bv = *(const floatx4*)&brow[c4];
                floatx4 r;
#pragma unroll
                for (int z = 0; z < 4; ++z) r[z] = wgt * (v[z] + bv[z]);
                if (ACC) {
                    floatx4 o = *(const floatx4*)&orow[c4];
#pragma unroll
                    for (int z = 0; z < 4; ++z) r[z] += o[z];
                }
                *(floatx4*)&orow[c4] = r;
            }
        }
    }
}

extern "C" void kernel_launch(void* const* d_in, const int* in_sizes, int n_in,
                              void* d_out, int out_size, void* d_ws, size_t ws_size,
                              hipStream_t stream) {
    const float* x  = (const float*)d_in[0];
    const float* Wg = (const float*)d_in[1];
    const float* bg = (const float*)d_in[2];
    const float* We = (const float*)d_in[3];
    const float* be = (const float*)d_in[4];
    float* out = (float*)d_out;

    int T = in_sizes[0] / DM;
    int n_slots = 2 * T;
    int NB = (n_slots + 255) / 256;

    char* ws = (char*)d_ws;
    size_t xb_bytes  = (size_t)T * DM * 2;
    size_t weT_bytes = (size_t)NE * DM * DF * 2;
    __bf16* Xb  = (__bf16*)ws;
    __bf16* WeT = (__bf16*)(ws + xb_bytes);
    char* rt = ws + xb_bytes + weT_bytes;
    int*   ntiles    = (int*)(rt + 0);
    int4*  wl        = (int4*)(rt + 64);                     // 2 * 136 int4
    int*   blk_cnt   = (int*)(rt + 64 + 2 * MAXT * 16);
    int*   blk_base  = (int*)((char*)blk_cnt + (size_t)NB * NBIN * 4);
    int*   tok_e     = (int*)((char*)blk_base + (size_t)NB * NBIN * 4);
    float* tok_w     = (float*)((char*)tok_e + (size_t)n_slots * 4);
    int*   gath_tok  = (int*)((char*)tok_w + (size_t)n_slots * 4);
    float* gath_w    = (float*)((char*)gath_tok + (size_t)n_slots * 4);

    convert_weT<<<dim3(DF / 256, DM / 8, NE), 256, 0, stream>>>(We, WeT);
    gate_kernel<<<(T + 3) / 4, 256, 0, stream>>>((const float4*)x, (const float4*)Wg,
                                                 bg, tok_e, tok_w, Xb, T);
    hist_kernel<<<NB, 256, 0, stream>>>(tok_e, blk_cnt, n_slots);
    scan_kernel<<<1, 256, 0, stream>>>(blk_cnt, blk_base, wl, ntiles, NB);
    scatter_kernel<<<NB, 256, 0, stream>>>(tok_e, tok_w, blk_base, gath_tok, gath_w, n_slots);

    expert_gemm_mfma<false><<<MAXT * 8, 256, 0, stream>>>(Xb, WeT, be, wl, ntiles,
                                                          gath_tok, gath_w, out);
    expert_gemm_mfma<true><<<MAXT * 8, 256, 0, stream>>>(Xb, WeT, be, wl + MAXT, ntiles + 1,
                                                         gath_tok, gath_w, out);
}

// Round 6
// 310.870 us; speedup vs baseline: 1.2457x; 1.0155x over previous
//
#include <hip/hip_runtime.h>
#include <math.h>

#define DM 1024
#define DF 1024
#define NE 8
#define NBIN 16          // (pass, expert) bins: bin = p*8 + e
#define MAXT 136         // max worklist tiles per pass
#define BM 128
#define BN 64
#define BKT 32
#define NT 32            // K-steps = DM/BKT

typedef __bf16 bf16x8 __attribute__((ext_vector_type(8)));
typedef __bf16 bf16x4 __attribute__((ext_vector_type(4)));
typedef float floatx4 __attribute__((ext_vector_type(4)));

typedef const __attribute__((address_space(1))) unsigned int* gas_t;
typedef __attribute__((address_space(3))) unsigned int* las_t;

__device__ __forceinline__ void ld_lds16(const void* g, void* l) {
    __builtin_amdgcn_global_load_lds((gas_t)g, (las_t)l, 16, 0, 0);
}

#define WAITVM(N) asm volatile("s_waitcnt vmcnt(" #N ")" ::: "memory")
#define BARRIER() do { asm volatile("" ::: "memory"); \
                       __builtin_amdgcn_s_barrier(); \
                       asm volatile("" ::: "memory"); } while (0)

// ---------------- ws layout ----------------
// [0, 33.5M)      Xb   bf16[T][1024]
// [33.5M, 50.3M)  WeT  bf16[8][1024][1024]  ([e][n][k])
// [50.3M, ...)    routing: ntiles[2], wl0/wl1 (int4[136] each), blk_cnt, blk_base,
//                 tok_e, tok_w, gath_tok, gath_w

__global__ void convert_weT(const float* __restrict__ We, __bf16* __restrict__ WeT) {
    int n  = blockIdx.x * 256 + threadIdx.x;
    int kc = blockIdx.y * 8;
    int e  = blockIdx.z;
    const float* src = We + ((size_t)e << 20) + (size_t)kc * DF + n;
    bf16x8 v;
#pragma unroll
    for (int j = 0; j < 8; ++j) v[j] = (__bf16)src[(size_t)j * DF];
    *(bf16x8*)&WeT[((size_t)e << 20) + (size_t)n * DM + kc] = v;
}

// fused: gate logits + top-2 + sigmoid + X -> bf16 conversion (X already in regs)
__global__ void gate_kernel(const float4* __restrict__ X4, const float4* __restrict__ Wg4,
                            const float* __restrict__ bg, int* __restrict__ tok_e,
                            float* __restrict__ tok_w, __bf16* __restrict__ Xb, int T) {
    int wid  = threadIdx.x >> 6;
    int lane = threadIdx.x & 63;
    int t = blockIdx.x * 4 + wid;
    if (t >= T) return;
    float acc[NE] = {};
    float4 xs[4];
#pragma unroll
    for (int c = 0; c < 4; ++c) {
        float4 xv = X4[(size_t)t * 256 + c * 64 + lane];
        xs[c] = xv;
#pragma unroll
        for (int e = 0; e < NE; ++e) {
            float4 wv = Wg4[e * 256 + c * 64 + lane];
            acc[e] += xv.x * wv.x + xv.y * wv.y + xv.z * wv.z + xv.w * wv.w;
        }
    }
    // convert this token's X row to bf16 (coalesced 8B stores)
#pragma unroll
    for (int c = 0; c < 4; ++c) {
        bf16x4 v;
        v[0] = (__bf16)xs[c].x; v[1] = (__bf16)xs[c].y;
        v[2] = (__bf16)xs[c].z; v[3] = (__bf16)xs[c].w;
        *(bf16x4*)&Xb[(size_t)t * DM + c * 256 + lane * 4] = v;
    }
#pragma unroll
    for (int e = 0; e < NE; ++e) {
#pragma unroll
        for (int off = 32; off > 0; off >>= 1)
            acc[e] += __shfl_down(acc[e], off, 64);
    }
    if (lane == 0) {
        float l[NE];
#pragma unroll
        for (int e = 0; e < NE; ++e) l[e] = acc[e] + bg[e];
        int b0 = 0; float v0 = l[0];
        for (int e = 1; e < NE; ++e) if (l[e] > v0) { v0 = l[e]; b0 = e; }
        int b1 = -1; float v1 = -3.4e38f;
        for (int e = 0; e < NE; ++e) if (e != b0 && l[e] > v1) { v1 = l[e]; b1 = e; }
        tok_e[2 * t]     = b0;  tok_e[2 * t + 1] = b1;
        tok_w[2 * t]     = 1.f / (1.f + expf(-v0));
        tok_w[2 * t + 1] = 1.f / (1.f + expf(-v1));
    }
}

// per-block 16-bin histogram via ballots (no global atomics)
__global__ void hist_kernel(const int* __restrict__ tok_e, int* __restrict__ blk_cnt, int n) {
    int b = blockIdx.x, tid = threadIdx.x;
    int idx  = b * 256 + tid;
    int lane = tid & 63, w = tid >> 6;
    int bin = (idx < n) ? ((idx & 1) * NE + tok_e[idx]) : -1;
    __shared__ int wc[4][NBIN];
#pragma unroll
    for (int bx = 0; bx < NBIN; ++bx) {
        unsigned long long m = __ballot(bin == bx);
        if (lane == 0) wc[w][bx] = (int)__popcll(m);
    }
    __syncthreads();
    if (tid < NBIN) blk_cnt[b * NBIN + tid] = wc[0][tid] + wc[1][tid] + wc[2][tid] + wc[3][tid];
}

// scan over blocks + bins, and build the two GEMM worklists
__global__ void scan_kernel(const int* __restrict__ blk_cnt, int* __restrict__ blk_base,
                            int4* __restrict__ wl, int* __restrict__ ntiles, int NB) {
    __shared__ int c[2048];
    __shared__ int tot[NBIN], base[NBIN];
    int tid = threadIdx.x;
    for (int i = tid; i < NB * NBIN; i += 256) c[i] = blk_cnt[i];
    __syncthreads();
    if (tid < NBIN) {
        int s = 0;
        for (int b = 0; b < NB; ++b) s += c[b * NBIN + tid];
        tot[tid] = s;
    }
    __syncthreads();
    if (tid == 0) {
        int s = 0;
        for (int b = 0; b < NBIN; ++b) { base[b] = s; s += tot[b]; }
    }
    __syncthreads();
    if (tid < NBIN) {
        int run = base[tid];
        for (int b = 0; b < NB; ++b) { int v = c[b * NBIN + tid]; c[b * NBIN + tid] = run; run += v; }
    }
    __syncthreads();
    for (int i = tid; i < NB * NBIN; i += 256) blk_base[i] = c[i];
    if (tid == 0) {
        for (int p = 0; p < 2; ++p) {
            int nt = 0;
            for (int e = 0; e < NE; ++e) {
                int bin = p * NE + e;
                int cnt = tot[bin], sg = base[bin];
                for (int r0 = 0; r0 < cnt; r0 += BM)
                    wl[p * MAXT + nt++] = make_int4(e, r0, sg, cnt);
            }
            ntiles[p] = nt;
        }
    }
}

// deterministic rank-based scatter into 16 bins (no global atomics)
__global__ void scatter_kernel(const int* __restrict__ tok_e, const float* __restrict__ tok_w,
                               const int* __restrict__ blk_base, int* __restrict__ gath_tok,
                               float* __restrict__ gath_w, int n) {
    int b = blockIdx.x, tid = threadIdx.x;
    int idx  = b * 256 + tid;
    int lane = tid & 63, w = tid >> 6;
    bool act = idx < n;
    int bin = act ? ((idx & 1) * NE + tok_e[idx]) : -1;
    __shared__ int wc[4][NBIN], wb[4][NBIN];
    int myrank = 0;
#pragma unroll
    for (int bx = 0; bx < NBIN; ++bx) {
        unsigned long long m = __ballot(bin == bx);
        if (lane == 0) wc[w][bx] = (int)__popcll(m);
        if (bin == bx) myrank = (int)__popcll(m & ((1ull << lane) - 1ull));
    }
    __syncthreads();
    if (tid < NBIN) {
        int run = blk_base[b * NBIN + tid];
#pragma unroll
        for (int wv = 0; wv < 4; ++wv) { wb[wv][tid] = run; run += wc[wv][tid]; }
    }
    __syncthreads();
    if (act) {
        int pos = wb[w][bin] + myrank;
        gath_tok[pos] = idx >> 1;
        gath_w[pos]   = tok_w[idx];
    }
}

// 128x64 tile, BKT=32, 4 staging buffers, prefetch distance 3, counted vmcnt
// (never 0 in steady state), raw s_barrier. 48 KB LDS -> 3 blocks/CU.
// LDS element (r, kchunk c) stored at physical chunk c ^ ((r>>1)&3); the
// global source is pre-swizzled (rule #21) since global_load_lds writes linearly.
template <bool ACC>
__global__ __launch_bounds__(256) void expert_gemm_mfma(
        const __bf16* __restrict__ Xb, const __bf16* __restrict__ WeT,
        const float* __restrict__ be, const int4* __restrict__ wl,
        const int* __restrict__ ntiles, const int* __restrict__ gtok,
        const float* __restrict__ gw, float* __restrict__ out) {
    // chunked XCD swizzle (bijective: 2176 = 8 * 272): XCD k gets 17 consecutive
    // worklist tiles x all 16 col-blocks -> A-rows and B-panels L2-resident per XCD
    int sw = (blockIdx.x & 7) * (2 * MAXT) + (blockIdx.x >> 3);
    int tix  = sw >> 4;
    int col0 = (sw & 15) * BN;
    if (tix >= ntiles[0]) return;
    int4 ent = wl[tix];
    int e = ent.x, row0 = ent.y, seg = ent.z, n_e = ent.w;

    // 48 KB: As = 4 buffers x 8 KB, Bs = 4 buffers x 4 KB.
    // Epilogue Cs (128x64 f32 = 32 KB) overlays the As region.
    __shared__ __align__(16) char smem[49152];
    __bf16* Asb = (__bf16*)smem;               // 4 x 4096 bf16
    __bf16* Bsb = (__bf16*)(smem + 32768);     // 4 x 2048 bf16
    float*  Cs  = (float*)smem;
    __shared__ int   s_tok[BM];
    __shared__ float s_w[BM];

    int tid = threadIdx.x;
    if (tid < BM) {
        int gr = row0 + tid;
        s_tok[tid] = (gr < n_e) ? gtok[seg + gr] : gtok[seg];
        s_w[tid]   = (gr < n_e) ? gw[seg + gr]   : 0.f;
    }
    __syncthreads();

    int lane = tid & 63, w = tid >> 6;
    int rsub = lane >> 2;                        // 0..15
    int kc   = (lane & 3) ^ ((lane >> 3) & 3);   // pre-swizzled global k-chunk

    // staging rows: A part p covers rows (p*4+w)*16 + rsub; B covers w*16+rsub
    const __bf16* aptr0 = Xb + (size_t)s_tok[w * 16 + rsub] * DM + kc * 8;
    const __bf16* aptr1 = Xb + (size_t)s_tok[(4 + w) * 16 + rsub] * DM + kc * 8;
    const __bf16* bptr  = WeT + ((size_t)e << 20)
                        + (size_t)(col0 + w * 16 + rsub) * DM + kc * 8;

    int wr  = (w >> 1) * 64;     // wave out-row base
    int wcc = (w & 1) * 32;      // wave out-col base
    int m16 = lane & 15, q4 = lane >> 4;
    int ccu = q4 ^ ((m16 >> 1) & 3);             // physical chunk for LDS reads

    floatx4 acc[4][2] = {};

#define STAGE(B, KS) do { \
    ld_lds16(aptr0 + (KS) * BKT, Asb + (B) * 4096 + w * 512); \
    ld_lds16(aptr1 + (KS) * BKT, Asb + (B) * 4096 + (4 + w) * 512); \
    ld_lds16(bptr  + (KS) * BKT, Bsb + (B) * 2048 + w * 512); } while (0)

#define COMP(B) do { \
    bf16x8 af[4], bfr[2]; \
    _Pragma("unroll") \
    for (int i = 0; i < 4; ++i) \
        af[i] = *(const bf16x8*)&Asb[(B) * 4096 + (wr + i * 16 + m16) * 32 + ccu * 8]; \
    _Pragma("unroll") \
    for (int j = 0; j < 2; ++j) \
        bfr[j] = *(const bf16x8*)&Bsb[(B) * 2048 + (wcc + j * 16 + m16) * 32 + ccu * 8]; \
    _Pragma("unroll") \
    for (int i = 0; i < 4; ++i) \
        _Pragma("unroll") \
        for (int j = 0; j < 2; ++j) \
            acc[i][j] = __builtin_amdgcn_mfma_f32_16x16x32_bf16(af[i], bfr[j], acc[i][j], 0, 0, 0); \
    } while (0)

    // prologue: 3 tiles in flight
    STAGE(0, 0); STAGE(1, 1); STAGE(2, 2);
    WAITVM(6);                 // tile 0 landed (this wave's oldest 3 loads)
    BARRIER();

    // steady state: compute k, free its buffer, stage k+3, ensure k+1 ready
    for (int kk = 0; kk < NT - 4; kk += 4) {
        COMP(0); BARRIER(); STAGE(3, kk + 3); WAITVM(6); BARRIER();
        COMP(1); BARRIER(); STAGE(0, kk + 4); WAITVM(6); BARRIER();
        COMP(2); BARRIER(); STAGE(1, kk + 5); WAITVM(6); BARRIER();
        COMP(3); BARRIER(); STAGE(2, kk + 6); WAITVM(6); BARRIER();
    }
    // k = 28..31 peeled drain
    COMP(0); BARRIER(); STAGE(3, NT - 1); WAITVM(6); BARRIER();
    COMP(1); BARRIER(); WAITVM(3); BARRIER();
    COMP(2); BARRIER(); WAITVM(0); BARRIER();
    COMP(3); BARRIER();            // all LDS reads done -> Cs overlay safe

#undef STAGE
#undef COMP

    // ---- epilogue: transpose acc through LDS (XOR-swizzled quads), then
    // full-line float4 writes / RMW: 4-lane groups cover 64-B contiguous runs ----
    // C/D fragment layout: row = wr + i*16 + q4*4 + rg, col = wcc + j*16 + m16
#pragma unroll
    for (int j = 0; j < 2; ++j) {
#pragma unroll
        for (int i = 0; i < 4; ++i) {
#pragma unroll
            for (int rg = 0; rg < 4; ++rg) {
                int rl = wr + i * 16 + q4 * 4 + rg;
                int cl = wcc + j * 16 + m16;
                int cq = (cl >> 2) ^ (rl & 15);        // swizzled quad (16/row)
                Cs[rl * 64 + cq * 4 + (cl & 3)] = acc[i][j][rg];
            }
        }
    }
    BARRIER();

    // reader: 4 lanes/row, two row-halves per thread -> all 128 rows
#pragma unroll
    for (int rh = 0; rh < 2; ++rh) {
        int rr = w * 32 + rh * 16 + (lane >> 2);
        int gr2 = row0 + rr;
        if (gr2 < n_e) {
            int tok = s_tok[rr];
            float wgt = s_w[rr];
            float* orow = out + (size_t)tok * DF + col0;
            const float* brow = be + e * DF + col0;
#pragma unroll
            for (int kq = 0; kq < 4; ++kq) {
                int cq_log = kq * 4 + (lane & 3);      // logical quad 0..15
                int c4 = cq_log * 4;
                floatx4 v  = *(const floatx4*)&Cs[rr * 64 + ((cq_log ^ (rr & 15)) * 4)];
                floatx4 bv = *(const floatx4*)&brow[c4];
                floatx4 r;
#pragma unroll
                for (int z = 0; z < 4; ++z) r[z] = wgt * (v[z] + bv[z]);
                if (ACC) {
                    floatx4 o = *(const floatx4*)&orow[c4];
#pragma unroll
                    for (int z = 0; z < 4; ++z) r[z] += o[z];
                }
                *(floatx4*)&orow[c4] = r;
            }
        }
    }
}

extern "C" void kernel_launch(void* const* d_in, const int* in_sizes, int n_in,
                              void* d_out, int out_size, void* d_ws, size_t ws_size,
                              hipStream_t stream) {
    const float* x  = (const float*)d_in[0];
    const float* Wg = (const float*)d_in[1];
    const float* bg = (const float*)d_in[2];
    const float* We = (const float*)d_in[3];
    const float* be = (const float*)d_in[4];
    float* out = (float*)d_out;

    int T = in_sizes[0] / DM;
    int n_slots = 2 * T;
    int NB = (n_slots + 255) / 256;

    char* ws = (char*)d_ws;
    size_t xb_bytes  = (size_t)T * DM * 2;
    size_t weT_bytes = (size_t)NE * DM * DF * 2;
    __bf16* Xb  = (__bf16*)ws;
    __bf16* WeT = (__bf16*)(ws + xb_bytes);
    char* rt = ws + xb_bytes + weT_bytes;
    int*   ntiles    = (int*)(rt + 0);
    int4*  wl        = (int4*)(rt + 64);                     // 2 * 136 int4
    int*   blk_cnt   = (int*)(rt + 64 + 2 * MAXT * 16);
    int*   blk_base  = (int*)((char*)blk_cnt + (size_t)NB * NBIN * 4);
    int*   tok_e     = (int*)((char*)blk_base + (size_t)NB * NBIN * 4);
    float* tok_w     = (float*)((char*)tok_e + (size_t)n_slots * 4);
    int*   gath_tok  = (int*)((char*)tok_w + (size_t)n_slots * 4);
    float* gath_w    = (float*)((char*)gath_tok + (size_t)n_slots * 4);

    convert_weT<<<dim3(DF / 256, DM / 8, NE), 256, 0, stream>>>(We, WeT);
    gate_kernel<<<(T + 3) / 4, 256, 0, stream>>>((const float4*)x, (const float4*)Wg,
                                                 bg, tok_e, tok_w, Xb, T);
    hist_kernel<<<NB, 256, 0, stream>>>(tok_e, blk_cnt, n_slots);
    scan_kernel<<<1, 256, 0, stream>>>(blk_cnt, blk_base, wl, ntiles, NB);
    scatter_kernel<<<NB, 256, 0, stream>>>(tok_e, tok_w, blk_base, gath_tok, gath_w, n_slots);

    expert_gemm_mfma<false><<<MAXT * 16, 256, 0, stream>>>(Xb, WeT, be, wl, ntiles,
                                                           gath_tok, gath_w, out);
    expert_gemm_mfma<true><<<MAXT * 16, 256, 0, stream>>>(Xb, WeT, be, wl + MAXT, ntiles + 1,
                                                          gath_tok, gath_w, out);
}